// Round 1
// baseline (2922.542 us; speedup 1.0000x reference)
//
#include <hip/hip_runtime.h>

typedef unsigned int uint;
typedef _Float16 f16;
typedef _Float16 f16x2 __attribute__((ext_vector_type(2)));
typedef _Float16 f16x8 __attribute__((ext_vector_type(8)));
typedef float f32x4 __attribute__((ext_vector_type(4)));

#define N_TYPES 10000
#define HID 256
#define G4 1024
#define BATCH 32
#define SEQ 1024

// ---------------- K1: path table: path[n][h] = sum_d cumw_d * emb[anc[n,d]][h]
__global__ void k_path(const int* __restrict__ anc, const float* __restrict__ weight,
                       const float* __restrict__ emb, int D, f16* __restrict__ path) {
  int n = blockIdx.x;
  int h = threadIdx.x;
  float acc = 0.f, cw = 1.f;
  for (int d = 0; d < D; ++d) {
    int a = anc[n * D + d];
    if (a < 0) break;
    acc += cw * emb[a * HID + h];
    cw *= weight[a];
  }
  path[n * HID + h] = (f16)acc;
}

// ---------------- K0: convert W_ih -> f16, W_hh -> transposed packed f16 pairs, bias = b_ih+b_hh
__global__ void k_conv(const float* __restrict__ wih, const float* __restrict__ whh,
                       const float* __restrict__ bih, const float* __restrict__ bhh,
                       f16* __restrict__ wih_h, uint* __restrict__ whh_t,
                       float* __restrict__ bias) {
  int i = blockIdx.x * 256 + threadIdx.x;   // 262144 threads
  wih_h[i] = (f16)wih[i];
  if (i < G4 * 128) {                       // 131072 u32 of packed W_hh
    int row = i >> 7, p = i & 127;
    f16x2 v;
    v.x = (f16)whh[row * HID + 2 * p];
    v.y = (f16)whh[row * HID + 2 * p + 1];
    whh_t[p * G4 + row] = __builtin_bit_cast(uint, v);  // [128 kpair][1024 row]
  }
  if (i < G4) bias[i] = bih[i] + bhh[i];
}

// ---------------- K2: proj[n][r] = sum_k path[n][k]*W_ih[r][k] + bias[r]   (M=10000,N=1024,K=256)
#define BM 128
#define BN 128
#define BK 64
#define LPAD 72
__global__ __launch_bounds__(256) void k_gemm(const f16* __restrict__ A,
                                              const f16* __restrict__ Bw,
                                              const float* __restrict__ bias,
                                              f16* __restrict__ C) {
  __shared__ f16 sA[BM][LPAD];
  __shared__ f16 sB[BN][LPAD];
  int m0 = blockIdx.x * BM, n0 = blockIdx.y * BN;
  int tid = threadIdx.x;
  int wid = tid >> 6, lane = tid & 63;
  int wm = wid & 1, wn = wid >> 1;
  f32x4 acc[4][4] = {};
  for (int k0 = 0; k0 < 256; k0 += BK) {
    __syncthreads();
    int r = tid >> 3, kc = (tid & 7) * 8;
    for (int i = 0; i < 4; ++i) {
      int row = r + 32 * i;
      int gm = m0 + row;
      uint4 va = make_uint4(0u, 0u, 0u, 0u);
      if (gm < N_TYPES) va = *(const uint4*)&A[gm * 256 + k0 + kc];
      *(uint4*)&sA[row][kc] = va;
      uint4 vb = *(const uint4*)&Bw[(n0 + row) * 256 + k0 + kc];
      *(uint4*)&sB[row][kc] = vb;
    }
    __syncthreads();
#pragma unroll
    for (int ks = 0; ks < 2; ++ks) {
      f16x8 af[4], bf[4];
      int kk = ks * 32 + (lane >> 4) * 8;
#pragma unroll
      for (int mt = 0; mt < 4; ++mt)
        af[mt] = *(const f16x8*)&sA[wm * 64 + mt * 16 + (lane & 15)][kk];
#pragma unroll
      for (int nt = 0; nt < 4; ++nt)
        bf[nt] = *(const f16x8*)&sB[wn * 64 + nt * 16 + (lane & 15)][kk];
#pragma unroll
      for (int mt = 0; mt < 4; ++mt)
#pragma unroll
        for (int nt = 0; nt < 4; ++nt)
          acc[mt][nt] = __builtin_amdgcn_mfma_f32_16x16x32_f16(af[mt], bf[nt], acc[mt][nt], 0, 0, 0);
    }
  }
#pragma unroll
  for (int mt = 0; mt < 4; ++mt)
#pragma unroll
    for (int nt = 0; nt < 4; ++nt)
#pragma unroll
      for (int q = 0; q < 4; ++q) {
        int row = m0 + wm * 64 + mt * 16 + (lane >> 4) * 4 + q;
        int col = n0 + wn * 64 + nt * 16 + (lane & 15);
        if (row < N_TYPES) C[row * G4 + col] = (f16)(acc[mt][nt][q] + bias[col]);
      }
}

// ---------------- K3: LSTM recurrence. 64 WGs: (b = bid&31, half = bid>>5), 512 threads.
// thread t: chunk=t>>7 (gate i/f/g/o), jloc=t&127, j=half*128+jloc, row=chunk*256+j.
// Weights: 128 packed f16-pair u32 in VGPRs. h broadcast: readlane -> v_dot2_f32_f16.
// Pairwise exchange of h halves via global hbuf + per-step flags (release/acquire agent).
__device__ __forceinline__ float dot2(uint wp, uint hp, float acc) {
#if __has_builtin(__builtin_amdgcn_fdot2)
  return __builtin_amdgcn_fdot2(__builtin_bit_cast(f16x2, wp),
                                __builtin_bit_cast(f16x2, hp), acc, false);
#else
  f16x2 a = __builtin_bit_cast(f16x2, wp);
  f16x2 b = __builtin_bit_cast(f16x2, hp);
  return acc + (float)a.x * (float)b.x + (float)a.y * (float)b.y;
#endif
}

__device__ __forceinline__ float sigm(float v) { return 1.f / (1.f + __expf(-v)); }
__device__ __forceinline__ float tanh_(float v) { return 1.f - 2.f / (__expf(2.f * v) + 1.f); }

__global__ __launch_bounds__(512, 2) void k_lstm(const int* __restrict__ evs,
                                                 const f16* __restrict__ proj,
                                                 const uint* __restrict__ whh_t,
                                                 uint* hbuf,   // [32][2][128]
                                                 uint* flags,  // [2][32][1024]
                                                 float* __restrict__ out) {
  int bid = blockIdx.x;
  int b = bid & 31, half = bid >> 5;
  int t = threadIdx.x;
  int chunk = t >> 7;
  int jloc = t & 127;
  int j = half * 128 + jloc;
  int row = chunk * 256 + j;
  int lane = t & 63;

  __shared__ float gl[512];
  __shared__ uint hl[64];

  uint w[128];
#pragma unroll
  for (int p = 0; p < 128; ++p) w[p] = whh_t[p * G4 + row];

  uint* myh = hbuf + b * 256;
  uint* pf = flags + ((1 - half) * 32 + b) * SEQ;
  uint* mf = flags + (half * 32 + b) * SEQ;
  const int* ev = evs + b * SEQ;
  const f16* projr = proj + row;

  float c = 0.f;

  for (int step = 0; step < SEQ; ++step) {
    // x gather for this step (issued early; consumed after matvec)
    int e = ev[step];
    float x = (float)projr[e * G4];

    uint hp0 = 0u, hp1 = 0u;
    if (step > 0) {
      if (t == 0) {
        const uint* f = pf + (step - 1);
        while (__hip_atomic_load(f, __ATOMIC_RELAXED, __HIP_MEMORY_SCOPE_AGENT) == 0u) {}
        (void)__hip_atomic_load(f, __ATOMIC_ACQUIRE, __HIP_MEMORY_SCOPE_AGENT);
      }
      __syncthreads();
      const uint* hb = myh + ((step - 1) & 1) * 128;
      if (half == 0) { hp0 = hl[lane]; hp1 = hb[64 + lane]; }
      else           { hp0 = hb[lane]; hp1 = hl[lane]; }
    }

    // matvec: acc = sum_k W_hh[row][k] * h[k]   (h pairs broadcast via readlane -> SGPR)
    int h0 = (int)hp0, h1 = (int)hp1;
    float a0 = 0.f, a1 = 0.f, a2 = 0.f, a3 = 0.f;
#pragma unroll
    for (int p = 0; p < 64; p += 4) {
      a0 = dot2(w[p + 0], (uint)__builtin_amdgcn_readlane(h0, p + 0), a0);
      a1 = dot2(w[p + 1], (uint)__builtin_amdgcn_readlane(h0, p + 1), a1);
      a2 = dot2(w[p + 2], (uint)__builtin_amdgcn_readlane(h0, p + 2), a2);
      a3 = dot2(w[p + 3], (uint)__builtin_amdgcn_readlane(h0, p + 3), a3);
    }
#pragma unroll
    for (int p = 0; p < 64; p += 4) {
      a0 = dot2(w[64 + p + 0], (uint)__builtin_amdgcn_readlane(h1, p + 0), a0);
      a1 = dot2(w[64 + p + 1], (uint)__builtin_amdgcn_readlane(h1, p + 1), a1);
      a2 = dot2(w[64 + p + 2], (uint)__builtin_amdgcn_readlane(h1, p + 2), a2);
      a3 = dot2(w[64 + p + 3], (uint)__builtin_amdgcn_readlane(h1, p + 3), a3);
    }
    float pre = ((a0 + a1) + (a2 + a3)) + x;

    // exchange gate pre-activations across chunks via LDS
    gl[t] = pre;
    __syncthreads();
    float gi = gl[jloc];
    float gf = gl[128 + jloc];
    float gg = gl[256 + jloc];
    float go = gl[384 + jloc];
    float iv = sigm(gi), fv = sigm(gf), gv = tanh_(gg), ov = sigm(go);
    c = fv * c + iv * gv;                 // replicated identically in all 4 chunks
    float hval = ov * tanh_(c);

    // publish h (chunk 0 only), write output
    float hn = __shfl_down(hval, 1);
    if (chunk == 0) {
      out[(step * BATCH + b) * HID + j] = hval;
      if ((jloc & 1) == 0) {
        f16x2 pk; pk.x = (f16)hval; pk.y = (f16)hn;
        uint pku = __builtin_bit_cast(uint, pk);
        int p = half * 64 + (jloc >> 1);
        myh[(step & 1) * 128 + p] = pku;   // global for partner
        hl[jloc >> 1] = pku;               // LDS for self
      }
    }
    __syncthreads();   // all stores done (vmcnt drained) before flag
    if (t == 0) {
      __hip_atomic_store(mf + step, 1u, __ATOMIC_RELEASE, __HIP_MEMORY_SCOPE_AGENT);
    }
  }
}

extern "C" void kernel_launch(void* const* d_in, const int* in_sizes, int n_in,
                              void* d_out, int out_size, void* d_ws, size_t ws_size,
                              hipStream_t stream) {
  (void)n_in; (void)out_size; (void)ws_size;
  const int* evs = (const int*)d_in[0];
  const int* anc = (const int*)d_in[1];
  const float* weight = (const float*)d_in[2];
  const float* emb = (const float*)d_in[3];
  const float* wih = (const float*)d_in[4];
  const float* whh = (const float*)d_in[5];
  const float* bih = (const float*)d_in[6];
  const float* bhh = (const float*)d_in[7];
  int D = in_sizes[1] / N_TYPES;

  char* ws = (char*)d_ws;
  f16* path = (f16*)(ws);                       // 10000*256*2   = 5,120,000
  f16* wih_h = (f16*)(ws + 5242880);            // 524,288
  uint* whh_t = (uint*)(ws + 5767168);          // 524,288
  float* bias = (float*)(ws + 6291456);         // 4,096
  f16* proj = (f16*)(ws + 6295552);             // 10000*1024*2  = 20,480,000
  uint* hbuf = (uint*)(ws + 26775552);          // 32,768
  uint* flags = (uint*)(ws + 26808320);         // 262,144
  float* out = (float*)d_out;

  hipMemsetAsync(flags, 0, 2 * 32 * SEQ * 4, stream);
  k_conv<<<1024, 256, 0, stream>>>(wih, whh, bih, bhh, wih_h, whh_t, bias);
  k_path<<<N_TYPES, 256, 0, stream>>>(anc, weight, emb, D, path);
  k_gemm<<<dim3(79, 8), 256, 0, stream>>>(path, wih_h, bias, proj);
  k_lstm<<<64, 512, 0, stream>>>(evs, proj, whh_t, hbuf, flags, out);
}